// Round 1
// baseline (2448.784 us; speedup 1.0000x reference)
//
#include <hip/hip_runtime.h>
#include <hip/hip_bf16.h>

typedef __attribute__((ext_vector_type(8))) short short8;
typedef float f32x4 __attribute__((ext_vector_type(4)));

#define DIM   512
#define HID   2048
#define NB    512
#define ROWSZ (513*512)

// ---------------- one-time: f32 [R][C] -> bf16 [C][R] ----------------
__global__ void k_transpose_bf16(const float* __restrict__ src,
                                 __hip_bfloat16* __restrict__ dst,
                                 int R, int C) {
  __shared__ float tile[32][33];
  int c0 = blockIdx.x * 32, r0 = blockIdx.y * 32;
  int tx = threadIdx.x & 31, ty = threadIdx.x >> 5;
  for (int i = 0; i < 32; i += 8)
    tile[ty + i][tx] = src[(size_t)(r0 + ty + i) * C + c0 + tx];
  __syncthreads();
  for (int i = 0; i < 32; i += 8)
    dst[(size_t)(c0 + ty + i) * R + r0 + tx] = __float2bfloat16(tile[tx][ty + i]);
}

// ---------------- init: copy state, write out[0] ----------------
__global__ void k_init(const float* __restrict__ y0, const float* __restrict__ Dy0,
                       float* __restrict__ y, float* __restrict__ Dy,
                       float* __restrict__ out) {
  int b = blockIdx.x, t = threadIdx.x;
  if (b == 0) {
    for (int i = t; i < DIM; i += 256) { float v = y0[i]; y[i] = v; out[i] = v; }
  } else {
    int e = (b - 1) * 1024 + t * 4;
    float4 v = *(const float4*)&Dy0[e];
    *(float4*)&Dy[e] = v;
    *(float4*)&out[DIM + e] = v;
  }
}

// ---------------- coef: ytmp=y+c*dyk; h=ytmp@W1+b1; a,c1,c2; V->bf16 ----------------
__global__ void k_coef(const float* __restrict__ y, const float* __restrict__ dyk_prev,
                       const float* __restrict__ Dy, const float* __restrict__ dDyk_prev,
                       float c, const float* __restrict__ W1, const float* __restrict__ b1,
                       float* __restrict__ a_s, float* __restrict__ c1_s,
                       float* __restrict__ c2_s, __hip_bfloat16* __restrict__ Vbf) {
  int t = threadIdx.x;
  if (blockIdx.x < 32) {
    __shared__ float yt[DIM];
    __shared__ float part[4][64];
    for (int i = t; i < DIM; i += 256) {
      float v = y[i];
      if (c != 0.0f) v += c * dyk_prev[i];
      yt[i] = v;
    }
    __syncthreads();
    int tj = t & 63, td = t >> 6;
    int j = blockIdx.x * 64 + tj;
    float s = 0.f;
    for (int d = td * 128; d < td * 128 + 128; ++d)
      s += yt[d] * W1[(size_t)d * HID + j];
    part[td][tj] = s;
    __syncthreads();
    if (td == 0) {
      float h = part[0][tj] + part[1][tj] + part[2][tj] + part[3][tj] + b1[j];
      float a = tanhf(h);
      float ap = 1.f - a * a;
      a_s[j] = a; c1_s[j] = ap; c2_s[j] = -a * ap;
    }
  } else {
    int vb = blockIdx.x - 32;  // 0..63
    const float4* Dy4 = (const float4*)Dy;
    const float4* K4  = (const float4*)dDyk_prev;
    for (int i = 0; i < 4; ++i) {
      int idx4 = vb * 1024 + i * 256 + t;
      float4 v = Dy4[idx4];
      if (c != 0.0f) {
        float4 k = K4[idx4];
        v.x += c * k.x; v.y += c * k.y; v.z += c * k.z; v.w += c * k.w;
      }
      int e = idx4 * 4;
      Vbf[e + 0] = __float2bfloat16(v.x);
      Vbf[e + 1] = __float2bfloat16(v.y);
      Vbf[e + 2] = __float2bfloat16(v.z);
      Vbf[e + 3] = __float2bfloat16(v.w);
    }
  }
}

// ---------------- GEMM1: g = Vbf @ W1^T(bf16), t = c1*g + c2*g^2 -> tbuf(bf16) ----------------
// A: Vbf [NB][DIM] row-major, B: W1t [HID][DIM] row-major (k-contiguous both)
__global__ __launch_bounds__(256) void k_gemm1(
    const __hip_bfloat16* __restrict__ Abf, const __hip_bfloat16* __restrict__ Btbf,
    const float* __restrict__ c1_s, const float* __restrict__ c2_s,
    __hip_bfloat16* __restrict__ tbuf) {
  __shared__ __align__(16) short As[64 * 72];
  __shared__ __align__(16) short Bs[64 * 72];
  const short* Ag = (const short*)Abf;
  const short* Bg = (const short*)Btbf;
  int m0 = blockIdx.x * 64;        // neighbor rows
  int n0 = blockIdx.y * 64;        // hidden cols
  int t = threadIdx.x;
  int w = t >> 6, lane = t & 63;
  int quad = lane >> 4, l16 = lane & 15;
  int wm = (w & 1) * 32, wn = (w >> 1) * 32;
  f32x4 acc[2][2] = {};
  for (int k0 = 0; k0 < DIM; k0 += 64) {
    __syncthreads();
    for (int i = 0; i < 2; ++i) {
      int L = t + i * 256;
      int r = L >> 3, c8 = (L & 7) * 8;
      *(uint4*)&As[r * 72 + c8] = *(const uint4*)&Ag[(m0 + r) * DIM + k0 + c8];
      *(uint4*)&Bs[r * 72 + c8] = *(const uint4*)&Bg[(n0 + r) * DIM + k0 + c8];
    }
    __syncthreads();
    for (int kk = 0; kk < 64; kk += 32) {
      short8 a0 = *(const short8*)&As[(wm + l16) * 72 + kk + quad * 8];
      short8 a1 = *(const short8*)&As[(wm + 16 + l16) * 72 + kk + quad * 8];
      short8 b0 = *(const short8*)&Bs[(wn + l16) * 72 + kk + quad * 8];
      short8 b1 = *(const short8*)&Bs[(wn + 16 + l16) * 72 + kk + quad * 8];
      acc[0][0] = __builtin_amdgcn_mfma_f32_16x16x32_bf16(a0, b0, acc[0][0], 0, 0, 0);
      acc[0][1] = __builtin_amdgcn_mfma_f32_16x16x32_bf16(a0, b1, acc[0][1], 0, 0, 0);
      acc[1][0] = __builtin_amdgcn_mfma_f32_16x16x32_bf16(a1, b0, acc[1][0], 0, 0, 0);
      acc[1][1] = __builtin_amdgcn_mfma_f32_16x16x32_bf16(a1, b1, acc[1][1], 0, 0, 0);
    }
  }
  for (int tn = 0; tn < 2; ++tn) {
    int col = n0 + wn + tn * 16 + l16;
    float C1 = c1_s[col], C2 = c2_s[col];
    for (int tm = 0; tm < 2; ++tm)
      for (int r = 0; r < 4; ++r) {
        int row = m0 + wm + tm * 16 + quad * 4 + r;
        float g = acc[tm][tn][r];
        tbuf[(size_t)row * HID + col] = __float2bfloat16(C1 * g + C2 * g * g);
      }
  }
}

// ---------------- GEMM2: dDy = tbuf @ W2 (bf16 mfma), plus exact f32 dy blocks ----------------
// A: tbuf [NB][HID], B: W2t [DIM][HID]
__global__ __launch_bounds__(256) void k_gemm2(
    const __hip_bfloat16* __restrict__ Abf, const __hip_bfloat16* __restrict__ Btbf,
    const float* __restrict__ a_s, const float* __restrict__ W2, const float* __restrict__ b2,
    float* __restrict__ dDy_out, float* __restrict__ dy_out) {
  int bid = blockIdx.x, t = threadIdx.x;
  if (bid < 64) {
    __shared__ __align__(16) short As[64 * 72];
    __shared__ __align__(16) short Bs[64 * 72];
    const short* Ag = (const short*)Abf;
    const short* Bg = (const short*)Btbf;
    int m0 = (bid & 7) * 64;   // neighbor rows
    int n0 = (bid >> 3) * 64;  // dim cols
    int w = t >> 6, lane = t & 63;
    int quad = lane >> 4, l16 = lane & 15;
    int wm = (w & 1) * 32, wn = (w >> 1) * 32;
    f32x4 acc[2][2] = {};
    for (int k0 = 0; k0 < HID; k0 += 64) {
      __syncthreads();
      for (int i = 0; i < 2; ++i) {
        int L = t + i * 256;
        int r = L >> 3, c8 = (L & 7) * 8;
        *(uint4*)&As[r * 72 + c8] = *(const uint4*)&Ag[(m0 + r) * HID + k0 + c8];
        *(uint4*)&Bs[r * 72 + c8] = *(const uint4*)&Bg[(n0 + r) * HID + k0 + c8];
      }
      __syncthreads();
      for (int kk = 0; kk < 64; kk += 32) {
        short8 a0 = *(const short8*)&As[(wm + l16) * 72 + kk + quad * 8];
        short8 a1 = *(const short8*)&As[(wm + 16 + l16) * 72 + kk + quad * 8];
        short8 b0 = *(const short8*)&Bs[(wn + l16) * 72 + kk + quad * 8];
        short8 b1 = *(const short8*)&Bs[(wn + 16 + l16) * 72 + kk + quad * 8];
        acc[0][0] = __builtin_amdgcn_mfma_f32_16x16x32_bf16(a0, b0, acc[0][0], 0, 0, 0);
        acc[0][1] = __builtin_amdgcn_mfma_f32_16x16x32_bf16(a0, b1, acc[0][1], 0, 0, 0);
        acc[1][0] = __builtin_amdgcn_mfma_f32_16x16x32_bf16(a1, b0, acc[1][0], 0, 0, 0);
        acc[1][1] = __builtin_amdgcn_mfma_f32_16x16x32_bf16(a1, b1, acc[1][1], 0, 0, 0);
      }
    }
    for (int tn = 0; tn < 2; ++tn)
      for (int tm = 0; tm < 2; ++tm)
        for (int r = 0; r < 4; ++r) {
          int row = m0 + wm + tm * 16 + quad * 4 + r;
          int col = n0 + wn + tn * 16 + l16;
          dDy_out[(size_t)row * DIM + col] = acc[tm][tn][r];
        }
  } else {
    // exact f32 dy: dy_i = sum_j a[j] * W2[j][i] + b2[i]; 16 blocks x 32 cols
    __shared__ float aLds[HID];
    __shared__ float part[8][32];
    int db = bid - 64;
    for (int i = t; i < HID; i += 256) aLds[i] = a_s[i];
    __syncthreads();
    int ti = t & 31, tj = t >> 5;  // tj 0..7
    int i = db * 32 + ti;
    float s = 0.f;
    for (int j = tj * 256; j < tj * 256 + 256; ++j)
      s += aLds[j] * W2[(size_t)j * DIM + i];
    part[tj][ti] = s;
    __syncthreads();
    if (tj == 0) {
      float r = 0.f;
      for (int q = 0; q < 8; ++q) r += part[q][ti];
      dy_out[i] = r + b2[i];
    }
  }
}

// ---------------- RK4 combine (+ optional save to out) ----------------
__global__ void k_combine(float* __restrict__ y, float* __restrict__ Dy,
                          const float* __restrict__ dyk, const float* __restrict__ dDyk,
                          float dt6, int save_idx, float* __restrict__ out) {
  int b = blockIdx.x, t = threadIdx.x;
  if (b == 0) {
    for (int i = t; i < DIM; i += 256) {
      float v = y[i] + dt6 * (dyk[i] + 2.f * dyk[DIM + i] + 2.f * dyk[2 * DIM + i] + dyk[3 * DIM + i]);
      y[i] = v;
      if (save_idx > 0) out[(size_t)save_idx * ROWSZ + i] = v;
    }
  } else {
    int e = (b - 1) * 1024 + t * 4;
    const int S = NB * DIM;
    float4 v  = *(float4*)&Dy[e];
    float4 k1 = *(const float4*)&dDyk[e];
    float4 k2 = *(const float4*)&dDyk[S + e];
    float4 k3 = *(const float4*)&dDyk[2 * S + e];
    float4 k4 = *(const float4*)&dDyk[3 * S + e];
    v.x += dt6 * (k1.x + 2.f * k2.x + 2.f * k3.x + k4.x);
    v.y += dt6 * (k1.y + 2.f * k2.y + 2.f * k3.y + k4.y);
    v.z += dt6 * (k1.z + 2.f * k2.z + 2.f * k3.z + k4.z);
    v.w += dt6 * (k1.w + 2.f * k2.w + 2.f * k3.w + k4.w);
    *(float4*)&Dy[e] = v;
    if (save_idx > 0) *(float4*)&out[(size_t)save_idx * ROWSZ + DIM + e] = v;
  }
}

extern "C" void kernel_launch(void* const* d_in, const int* in_sizes, int n_in,
                              void* d_out, int out_size, void* d_ws, size_t ws_size,
                              hipStream_t stream) {
  const float* y0  = (const float*)d_in[1];
  const float* Dy0 = (const float*)d_in[2];
  const float* W1  = (const float*)d_in[3];
  const float* b1  = (const float*)d_in[4];
  const float* W2  = (const float*)d_in[5];
  const float* b2  = (const float*)d_in[6];
  float* out = (float*)d_out;

  char* p = (char*)d_ws;
  auto alloc = [&](size_t bytes) {
    char* r = p;
    p += (bytes + 255) & ~(size_t)255;
    return r;
  };
  float* y    = (float*)alloc(DIM * 4);
  float* Dy   = (float*)alloc((size_t)NB * DIM * 4);
  float* dyk  = (float*)alloc(4 * DIM * 4);
  float* dDyk = (float*)alloc(4 * (size_t)NB * DIM * 4);
  float* a_s  = (float*)alloc(HID * 4);
  float* c1_s = (float*)alloc(HID * 4);
  float* c2_s = (float*)alloc(HID * 4);
  __hip_bfloat16* W1t  = (__hip_bfloat16*)alloc((size_t)HID * DIM * 2);
  __hip_bfloat16* W2t  = (__hip_bfloat16*)alloc((size_t)DIM * HID * 2);
  __hip_bfloat16* Vbf  = (__hip_bfloat16*)alloc((size_t)NB * DIM * 2);
  __hip_bfloat16* tbuf = (__hip_bfloat16*)alloc((size_t)NB * HID * 2);

  const float dt = 0.0625f;  // (1/8 interval) / 2 substeps, uniform ts
  k_transpose_bf16<<<dim3(HID / 32, DIM / 32), 256, 0, stream>>>(W1, W1t, DIM, HID);
  k_transpose_bf16<<<dim3(DIM / 32, HID / 32), 256, 0, stream>>>(W2, W2t, HID, DIM);
  k_init<<<257, 256, 0, stream>>>(y0, Dy0, y, Dy, out);

  for (int ss = 0; ss < 16; ++ss) {
    for (int s = 0; s < 4; ++s) {
      float c = (s == 0) ? 0.f : (s == 3 ? dt : 0.5f * dt);
      const float* dyp  = dyk  + (s ? (s - 1) * DIM : 0);
      const float* dDyp = dDyk + (s ? (size_t)(s - 1) * NB * DIM : 0);
      k_coef<<<96, 256, 0, stream>>>(y, dyp, Dy, dDyp, c, W1, b1, a_s, c1_s, c2_s, Vbf);
      k_gemm1<<<dim3(NB / 64, HID / 64), 256, 0, stream>>>(Vbf, W1t, c1_s, c2_s, tbuf);
      k_gemm2<<<80, 256, 0, stream>>>(tbuf, W2t, a_s, W2, b2,
                                      dDyk + (size_t)s * NB * DIM, dyk + s * DIM);
    }
    int save_idx = (ss & 1) ? (ss / 2 + 1) : 0;
    k_combine<<<257, 256, 0, stream>>>(y, Dy, dyk, dDyk, dt / 6.f, save_idx, out);
  }
}

// Round 2
// 2046.616 us; speedup vs baseline: 1.1965x; 1.1965x over previous
//
#include <hip/hip_runtime.h>
#include <hip/hip_bf16.h>

typedef __attribute__((ext_vector_type(8))) short short8;
typedef float f32x4 __attribute__((ext_vector_type(4)));

#define DIM   512
#define HID   2048
#define NB    512
#define ROWSZ (513*512)
#define S_NB  (NB*DIM)

__device__ __forceinline__ short f2bf(float f) {
  __hip_bfloat16 h = __float2bfloat16(f);
  return *reinterpret_cast<short*>(&h);
}
__device__ __forceinline__ float bf2f(unsigned short s) {
  unsigned u = ((unsigned)s) << 16;
  return __uint_as_float(u);
}

// ---------------- one-time: f32 [R][C] -> bf16 [C][R] ----------------
__global__ void k_transpose_bf16(const float* __restrict__ src,
                                 __hip_bfloat16* __restrict__ dst,
                                 int R, int C) {
  __shared__ float tile[32][33];
  int c0 = blockIdx.x * 32, r0 = blockIdx.y * 32;
  int tx = threadIdx.x & 31, ty = threadIdx.x >> 5;
  for (int i = 0; i < 32; i += 8)
    tile[ty + i][tx] = src[(size_t)(r0 + ty + i) * C + c0 + tx];
  __syncthreads();
  for (int i = 0; i < 32; i += 8)
    dst[(size_t)(c0 + ty + i) * R + r0 + tx] = __float2bfloat16(tile[tx][ty + i]);
}

// ---------------- init: copy state, write out[0] ----------------
__global__ void k_init(const float* __restrict__ y0, const float* __restrict__ Dy0,
                       float* __restrict__ y, float* __restrict__ Dy,
                       float* __restrict__ out) {
  int b = blockIdx.x, t = threadIdx.x;
  if (b == 0) {
    for (int i = t; i < DIM; i += 256) { float v = y0[i]; y[i] = v; out[i] = v; }
  } else {
    int e = (b - 1) * 1024 + t * 4;
    float4 v = *(const float4*)&Dy0[e];
    *(float4*)&Dy[e] = v;
    *(float4*)&out[DIM + e] = v;
  }
}

// ---------------- K1: gemm1 (V inline) + h/tanh blocks ----------------
// gemm blocks (0..511): g = (Dy + c*dDy_prev) @ W1t^T  -> gbuf bf16 [NB][HID]
//   tile 32x64, A k-contig from f32 state, B = W1t [HID][DIM] k-contig bf16
// h blocks (512..543): yt = y + c*dyk_prev; h = yt@W1 + b1; a,c1,c2
__global__ __launch_bounds__(256) void k_stage1(
    const float* __restrict__ Dy, const float* __restrict__ dDy_prev,
    const float* __restrict__ y, const float* __restrict__ dy_prev,
    float c,
    const __hip_bfloat16* __restrict__ W1t, const float* __restrict__ W1,
    const float* __restrict__ b1,
    __hip_bfloat16* __restrict__ gbuf,
    float* __restrict__ a_s, float* __restrict__ c1_s, float* __restrict__ c2_s) {
  int bid = blockIdx.x, t = threadIdx.x;
  if (bid < 512) {
    __shared__ __align__(16) short As[32 * 72];
    __shared__ __align__(16) short Bs[64 * 72];
    const short* Bg = (const short*)W1t;
    int m0 = (bid & 15) * 32;
    int n0 = (bid >> 4) * 64;
    int w = t >> 6, lane = t & 63, quad = lane >> 4, l16 = lane & 15;
    int wm = (w & 1) * 16, wn = (w >> 1) * 32;
    int ra = t >> 3, ca = (t & 7) * 8;   // A: 32x64, 8 elts/thread
    int rb = t >> 2, cb = (t & 3) * 16;  // B: 64x64, 16 elts/thread
    f32x4 acc0 = {}, acc1 = {};
    for (int k0 = 0; k0 < DIM; k0 += 64) {
      __syncthreads();
      size_t abase = (size_t)(m0 + ra) * DIM + k0 + ca;
      float4 v0 = *(const float4*)&Dy[abase];
      float4 v1 = *(const float4*)&Dy[abase + 4];
      if (c != 0.f) {
        float4 p0 = *(const float4*)&dDy_prev[abase];
        float4 p1 = *(const float4*)&dDy_prev[abase + 4];
        v0.x += c * p0.x; v0.y += c * p0.y; v0.z += c * p0.z; v0.w += c * p0.w;
        v1.x += c * p1.x; v1.y += c * p1.y; v1.z += c * p1.z; v1.w += c * p1.w;
      }
      short8 av;
      av[0] = f2bf(v0.x); av[1] = f2bf(v0.y); av[2] = f2bf(v0.z); av[3] = f2bf(v0.w);
      av[4] = f2bf(v1.x); av[5] = f2bf(v1.y); av[6] = f2bf(v1.z); av[7] = f2bf(v1.w);
      *(short8*)&As[ra * 72 + ca] = av;
      size_t bbase = (size_t)(n0 + rb) * DIM + k0 + cb;
      *(uint4*)&Bs[rb * 72 + cb]     = *(const uint4*)&Bg[bbase];
      *(uint4*)&Bs[rb * 72 + cb + 8] = *(const uint4*)&Bg[bbase + 8];
      __syncthreads();
      for (int kk = 0; kk < 64; kk += 32) {
        short8 a  = *(const short8*)&As[(wm + l16) * 72 + kk + quad * 8];
        short8 b0 = *(const short8*)&Bs[(wn + l16) * 72 + kk + quad * 8];
        short8 b1v = *(const short8*)&Bs[(wn + 16 + l16) * 72 + kk + quad * 8];
        acc0 = __builtin_amdgcn_mfma_f32_16x16x32_bf16(a, b0, acc0, 0, 0, 0);
        acc1 = __builtin_amdgcn_mfma_f32_16x16x32_bf16(a, b1v, acc1, 0, 0, 0);
      }
    }
    for (int r = 0; r < 4; ++r) {
      int row = m0 + wm + quad * 4 + r;
      gbuf[(size_t)row * HID + n0 + wn + l16]      = __float2bfloat16(acc0[r]);
      gbuf[(size_t)row * HID + n0 + wn + 16 + l16] = __float2bfloat16(acc1[r]);
    }
  } else {
    __shared__ float yt[DIM];
    __shared__ float part[4][64];
    for (int i = t; i < DIM; i += 256) {
      float v = y[i];
      if (c != 0.0f) v += c * dy_prev[i];
      yt[i] = v;
    }
    __syncthreads();
    int tj = t & 63, td = t >> 6;
    int j = (bid - 512) * 64 + tj;
    float s = 0.f;
    for (int d = td * 128; d < td * 128 + 128; ++d)
      s += yt[d] * W1[(size_t)d * HID + j];
    part[td][tj] = s;
    __syncthreads();
    if (td == 0) {
      float h = part[0][tj] + part[1][tj] + part[2][tj] + part[3][tj] + b1[j];
      float a = tanhf(h);
      float ap = 1.f - a * a;
      a_s[j] = a; c1_s[j] = ap; c2_s[j] = -a * ap;
    }
  }
}

// ---------------- K2: gemm2 (transform inline) + dy blocks (+ fused combine) ----
// gemm blocks (0..255): dDy = (c1*g + c2*g^2) @ W2t^T, tile 32x32, K=HID
// dy blocks (256..271): dy_i = sum_j a[j]*W2[j][i] + b2[i]
// if final: epilogue does RK4 combine (k4 from registers), updates y/Dy, saves out
__global__ __launch_bounds__(256) void k_stage2(
    const __hip_bfloat16* __restrict__ gbuf, const __hip_bfloat16* __restrict__ W2t,
    const float* __restrict__ c1_s, const float* __restrict__ c2_s,
    const float* __restrict__ a_s, const float* __restrict__ W2, const float* __restrict__ b2,
    float* __restrict__ dDy_out, float* __restrict__ dy_out,
    int final_stage,
    float* __restrict__ y, float* __restrict__ Dy,
    const float* __restrict__ dyk, const float* __restrict__ dDyk,
    float dt6, int save_idx, float* __restrict__ out) {
  int bid = blockIdx.x, t = threadIdx.x;
  if (bid < 256) {
    __shared__ __align__(16) short As[32 * 72];
    __shared__ __align__(16) short Bs[32 * 72];
    const short* Ag = (const short*)gbuf;
    const short* Bg = (const short*)W2t;
    int m0 = (bid & 15) * 32;
    int n0 = (bid >> 4) * 32;
    int w = t >> 6, lane = t & 63, quad = lane >> 4, l16 = lane & 15;
    int wm = (w & 1) * 16, wn = (w >> 1) * 16;
    int ra = t >> 3, ca = (t & 7) * 8;  // both tiles 32x64, 8 elts/thread
    f32x4 acc = {};
    for (int k0 = 0; k0 < HID; k0 += 64) {
      __syncthreads();
      // A with pointwise transform t = c1*g + c2*g^2
      uint4 g4 = *(const uint4*)&Ag[(size_t)(m0 + ra) * HID + k0 + ca];
      const unsigned short* gs = (const unsigned short*)&g4;
      float4 C1a = *(const float4*)&c1_s[k0 + ca];
      float4 C1b = *(const float4*)&c1_s[k0 + ca + 4];
      float4 C2a = *(const float4*)&c2_s[k0 + ca];
      float4 C2b = *(const float4*)&c2_s[k0 + ca + 4];
      float gg[8];
      for (int i = 0; i < 8; ++i) gg[i] = bf2f(gs[i]);
      short8 av;
      av[0] = f2bf(C1a.x * gg[0] + C2a.x * gg[0] * gg[0]);
      av[1] = f2bf(C1a.y * gg[1] + C2a.y * gg[1] * gg[1]);
      av[2] = f2bf(C1a.z * gg[2] + C2a.z * gg[2] * gg[2]);
      av[3] = f2bf(C1a.w * gg[3] + C2a.w * gg[3] * gg[3]);
      av[4] = f2bf(C1b.x * gg[4] + C2b.x * gg[4] * gg[4]);
      av[5] = f2bf(C1b.y * gg[5] + C2b.y * gg[5] * gg[5]);
      av[6] = f2bf(C1b.z * gg[6] + C2b.z * gg[6] * gg[6]);
      av[7] = f2bf(C1b.w * gg[7] + C2b.w * gg[7] * gg[7]);
      *(short8*)&As[ra * 72 + ca] = av;
      *(uint4*)&Bs[ra * 72 + ca] = *(const uint4*)&Bg[(size_t)(n0 + ra) * HID + k0 + ca];
      __syncthreads();
      for (int kk = 0; kk < 64; kk += 32) {
        short8 a = *(const short8*)&As[(wm + l16) * 72 + kk + quad * 8];
        short8 b = *(const short8*)&Bs[(wn + l16) * 72 + kk + quad * 8];
        acc = __builtin_amdgcn_mfma_f32_16x16x32_bf16(a, b, acc, 0, 0, 0);
      }
    }
    if (!final_stage) {
      for (int r = 0; r < 4; ++r) {
        int row = m0 + wm + quad * 4 + r;
        dDy_out[(size_t)row * DIM + n0 + wn + l16] = acc[r];
      }
    } else {
      for (int r = 0; r < 4; ++r) {
        int row = m0 + wm + quad * 4 + r;
        size_t e = (size_t)row * DIM + n0 + wn + l16;
        float k1 = dDyk[e], k2 = dDyk[S_NB + e], k3 = dDyk[2 * S_NB + e];
        float v = Dy[e] + dt6 * (k1 + 2.f * k2 + 2.f * k3 + acc[r]);
        Dy[e] = v;
        if (save_idx > 0) out[(size_t)save_idx * ROWSZ + DIM + e] = v;
      }
    }
  } else {
    __shared__ float aLds[HID];
    __shared__ float part[8][32];
    int db = bid - 256;
    for (int i = t; i < HID; i += 256) aLds[i] = a_s[i];
    __syncthreads();
    int ti = t & 31, tj = t >> 5;
    int i = db * 32 + ti;
    float s = 0.f;
    for (int j = tj * 256; j < tj * 256 + 256; ++j)
      s += aLds[j] * W2[(size_t)j * DIM + i];
    part[tj][ti] = s;
    __syncthreads();
    if (tj == 0) {
      float r = 0.f;
      for (int q = 0; q < 8; ++q) r += part[q][ti];
      float k4 = r + b2[i];
      if (!final_stage) {
        dy_out[i] = k4;
      } else {
        float v = y[i] + dt6 * (dyk[i] + 2.f * dyk[DIM + i] + 2.f * dyk[2 * DIM + i] + k4);
        y[i] = v;
        if (save_idx > 0) out[(size_t)save_idx * ROWSZ + i] = v;
      }
    }
  }
}

extern "C" void kernel_launch(void* const* d_in, const int* in_sizes, int n_in,
                              void* d_out, int out_size, void* d_ws, size_t ws_size,
                              hipStream_t stream) {
  const float* y0  = (const float*)d_in[1];
  const float* Dy0 = (const float*)d_in[2];
  const float* W1  = (const float*)d_in[3];
  const float* b1  = (const float*)d_in[4];
  const float* W2  = (const float*)d_in[5];
  const float* b2  = (const float*)d_in[6];
  float* out = (float*)d_out;

  char* p = (char*)d_ws;
  auto alloc = [&](size_t bytes) {
    char* r = p;
    p += (bytes + 255) & ~(size_t)255;
    return r;
  };
  float* y    = (float*)alloc(DIM * 4);
  float* Dy   = (float*)alloc((size_t)S_NB * 4);
  float* dyk  = (float*)alloc(3 * DIM * 4);
  float* dDyk = (float*)alloc(3 * (size_t)S_NB * 4);
  float* a_s  = (float*)alloc(HID * 4);
  float* c1_s = (float*)alloc(HID * 4);
  float* c2_s = (float*)alloc(HID * 4);
  __hip_bfloat16* W1t  = (__hip_bfloat16*)alloc((size_t)HID * DIM * 2);
  __hip_bfloat16* W2t  = (__hip_bfloat16*)alloc((size_t)DIM * HID * 2);
  __hip_bfloat16* gbuf = (__hip_bfloat16*)alloc((size_t)NB * HID * 2);

  const float dt = 0.0625f;  // (1/8)/2, uniform ts
  k_transpose_bf16<<<dim3(HID / 32, DIM / 32), 256, 0, stream>>>(W1, W1t, DIM, HID);
  k_transpose_bf16<<<dim3(DIM / 32, HID / 32), 256, 0, stream>>>(W2, W2t, HID, DIM);
  k_init<<<257, 256, 0, stream>>>(y0, Dy0, y, Dy, out);

  for (int ss = 0; ss < 16; ++ss) {
    for (int s = 0; s < 4; ++s) {
      float c = (s == 0) ? 0.f : (s == 3 ? dt : 0.5f * dt);
      const float* dyp  = dyk  + (s ? (s - 1) * DIM : 0);
      const float* dDyp = dDyk + (s ? (size_t)(s - 1) * S_NB : 0);
      k_stage1<<<544, 256, 0, stream>>>(Dy, dDyp, y, dyp, c, W1t, W1, b1,
                                        gbuf, a_s, c1_s, c2_s);
      int fin = (s == 3);
      int save_idx = (fin && (ss & 1)) ? (ss / 2 + 1) : 0;
      k_stage2<<<272, 256, 0, stream>>>(gbuf, W2t, c1_s, c2_s, a_s, W2, b2,
                                        dDyk + (size_t)s * S_NB, dyk + s * DIM,
                                        fin, y, Dy, dyk, dDyk,
                                        dt / 6.f, save_idx, out);
    }
  }
}